// Round 9
// baseline (155.614 us; speedup 1.0000x reference)
//
#include <hip/hip_runtime.h>
#include <stdint.h>

// ---------------------------------------------------------------------------
// SlidingWindowAttention: B=2, N=2048, C=1024, H=16, Dh=64, window=512 (half=256)
// fp16 MFMA pipeline (4 dispatches) — R18 configuration:
//   prep: x->fp16, W_qkv^T, W_proj^T
//   GEMM1: R15-exact 256x192 2-phase/K-tile counted vmcnt(7), A3/B2 buf
//   GEMM2: R17-exact 128x128 1-phase counted vmcnt(4), A3/B2 buf
//   attn v6 (R18): R11 compute byte-identical; K/V staging deepened to
//     3 buffers x 16KB (Q staged in buf2, reused after bq reg-reads with
//     lgkm+barrier certification), counted vmcnt(2)/(0) + raw s_barrier —
//     48 KiB LDS keeps 3 blocks/CU (R12's +7.4us retried WITHOUT its two
//     confounds: 64KB smem occupancy drop 3->2 blocks/CU, sched_barrier
//     fences; no fences here, occupancy preserved).
// Negative results (do NOT retry): R7 1-barrier dbuf BK=32 (+4.6us);
// R9 32x32x16 GEMM MFMA (+2.4us); R5 256q attn tiles (+8us); R10 raw-asm
// v_permlane32_swap (WRONG RESULTS); R12 attn counted-vmcnt w/ 64KB smem +
// sched_barrier fences (+7.4us — occupancy+fence confounds, see above);
// R13 __launch_bounds__(512,2) on 256² GEMM (spill); R14 drain0-per-tile
// (T3 gain IS T4, m218); R16 fine 4-phase m-quarter split (+3.1us).
// Pre-commit: if R18 total >= 152.6, revert attn to R11-exact and plateau.
// ---------------------------------------------------------------------------

typedef _Float16 f16x8 __attribute__((ext_vector_type(8)));
typedef _Float16 f16x4 __attribute__((ext_vector_type(4)));
typedef __fp16   fp16x2n __attribute__((ext_vector_type(2)));
typedef float    f32x2 __attribute__((ext_vector_type(2)));
typedef float    f32x4 __attribute__((ext_vector_type(4)));
typedef float    f32x16 __attribute__((ext_vector_type(16)));

#define MFMA16(a, b, c) __builtin_amdgcn_mfma_f32_16x16x32_f16((a), (b), (c), 0, 0, 0)
#define MFMA32(a, b, c) __builtin_amdgcn_mfma_f32_32x32x16_f16((a), (b), (c), 0, 0, 0)

__device__ __forceinline__ void gload16(const void* g, void* l) {
  __builtin_amdgcn_global_load_lds(
      (const __attribute__((address_space(1))) void*)g,
      (__attribute__((address_space(3))) void*)l, 16, 0, 0);
}

__device__ __forceinline__ unsigned pk2(float a, float b) {
  fp16x2n t = __builtin_amdgcn_cvt_pkrtz(a, b);
  return __builtin_bit_cast(unsigned, t);
}

// -------------------------- fused prep -------------------------------------
__global__ __launch_bounds__(256) void prep(const float* __restrict__ x,
                                            const float* __restrict__ wqkv,
                                            const float* __restrict__ wproj,
                                            _Float16* __restrict__ Xb,
                                            _Float16* __restrict__ Wqt,
                                            _Float16* __restrict__ Wpt) {
  __shared__ float t[64][65];
  const int id = blockIdx.x, tid = threadIdx.x;
  if (id < 4096) {
    int i = (id * 256 + tid) * 4;
    float4 v = *(const float4*)(x + i);
    f16x4 h;
    h[0] = (_Float16)v.x; h[1] = (_Float16)v.y;
    h[2] = (_Float16)v.z; h[3] = (_Float16)v.w;
    *(f16x4*)(Xb + i) = h;
    return;
  }
  const float* in; _Float16* out; int N, bx, by;
  if (id < 4864) { int tt = id - 4096; in = wqkv; out = Wqt; N = 3072; bx = tt % 48; by = tt / 48; }
  else           { int tt = id - 4864; in = wproj; out = Wpt; N = 1024; bx = tt & 15; by = tt >> 4; }
  const int n0 = bx * 64, k0 = by * 64;
  {
    int j = tid & 63;
#pragma unroll
    for (int p = 0; p < 16; p++) {
      int i = p * 4 + (tid >> 6);
      t[i][j] = in[(size_t)(k0 + i) * N + n0 + j];
    }
  }
  __syncthreads();
  {
    int i = tid & 63;
#pragma unroll
    for (int p = 0; p < 16; p++) {
      int j = p * 4 + (tid >> 6);
      out[(size_t)(n0 + j) * 1024 + k0 + i] = (_Float16)t[i][j];
    }
  }
}

// -------------------------- GEMM1: 256x192 2-phase counted (R15 exact) -----
__global__ __launch_bounds__(512) void gemm8p(const _Float16* __restrict__ A,
                                              const _Float16* __restrict__ Bt,
                                              _Float16* __restrict__ oh,
                                              _Float16* __restrict__ vt) {
  __shared__ __align__(16) char smem[147456];
  const int tid = threadIdx.x, wave = tid >> 6, lane = tid & 63;
  const int il = lane & 15, ih = lane >> 4;
  const int rs = lane >> 3, cp = lane & 7;
  const int bm = blockIdx.y * 256, bn = blockIdx.x * 192;
  const int wm = wave >> 2, wn = wave & 3;
  const int srow = wave * 8 + rs;

#define R15_STAGE_A(ABUF, T)                                                  \
  _Pragma("unroll") for (int hh = 0; hh < 4; hh++) {                          \
    int row = hh * 64 + srow;                                                 \
    int c = cp ^ (row & 7);                                                   \
    gload16(A + (size_t)(bm + row) * 1024 + (T) * 64 + c * 8,                 \
            smem + (ABUF) * 32768 + hh * 8192 + wave * 1024);                 \
  }
#define R15_STAGE_B(BBUF, T)                                                  \
  _Pragma("unroll") for (int hh = 0; hh < 3; hh++) {                          \
    int row = hh * 64 + srow;                                                 \
    int c = cp ^ (row & 7);                                                   \
    gload16(Bt + (size_t)(bn + row) * 1024 + (T) * 64 + c * 8,                \
            smem + 98304 + (BBUF) * 24576 + hh * 8192 + wave * 1024);         \
  }

  f32x4 acc[8][3] = {};

  R15_STAGE_A(0, 0);
  R15_STAGE_B(0, 0);
  R15_STAGE_A(1, 1);
  R15_STAGE_B(1, 1);
  asm volatile("s_waitcnt vmcnt(7)" ::: "memory");
  __builtin_amdgcn_s_barrier();

  int ta = 0, sa = 2;
#pragma unroll 1
  for (int t = 0; t < 16; t++) {
    const char* Abuf = (const char*)smem + ta * 32768;
    const char* Bbuf = (const char*)smem + 98304 + (t & 1) * 24576;
    f16x8 af[4][2], ag[4][2], bf[3][2];
#pragma unroll
    for (int m = 0; m < 4; m++) {
      int R = wm * 128 + m * 16 + il;
#pragma unroll
      for (int ks = 0; ks < 2; ks++)
        af[m][ks] = *(const f16x8*)(Abuf + R * 128 + (((ks * 4 + ih) ^ (R & 7)) * 16));
    }
#pragma unroll
    for (int n = 0; n < 3; n++) {
      int C = wn * 48 + n * 16 + il;
#pragma unroll
      for (int ks = 0; ks < 2; ks++)
        bf[n][ks] = *(const f16x8*)(Bbuf + C * 128 + (((ks * 4 + ih) ^ (C & 7)) * 16));
    }
    if (t < 14) { R15_STAGE_A(sa, t + 2); }
    asm volatile("s_waitcnt lgkmcnt(0)" ::: "memory");
    __builtin_amdgcn_s_barrier();
    __builtin_amdgcn_s_setprio(1);
#pragma unroll
    for (int m = 0; m < 4; m++)
#pragma unroll
      for (int n = 0; n < 3; n++)
#pragma unroll
        for (int ks = 0; ks < 2; ks++)
          acc[m][n] = MFMA16(af[m][ks], bf[n][ks], acc[m][n]);
    __builtin_amdgcn_s_setprio(0);
#pragma unroll
    for (int m = 0; m < 4; m++) {
      int R = wm * 128 + 64 + m * 16 + il;
#pragma unroll
      for (int ks = 0; ks < 2; ks++)
        ag[m][ks] = *(const f16x8*)(Abuf + R * 128 + (((ks * 4 + ih) ^ (R & 7)) * 16));
    }
    if (t < 14) { R15_STAGE_B(t & 1, t + 2); }
    __builtin_amdgcn_s_setprio(1);
#pragma unroll
    for (int m = 0; m < 4; m++)
#pragma unroll
      for (int n = 0; n < 3; n++)
#pragma unroll
        for (int ks = 0; ks < 2; ks++)
          acc[4 + m][n] = MFMA16(ag[m][ks], bf[n][ks], acc[4 + m][n]);
    __builtin_amdgcn_s_setprio(0);
    if (t <= 13) {
      asm volatile("s_waitcnt vmcnt(7)" ::: "memory");
    } else if (t == 14) {
      asm volatile("s_waitcnt vmcnt(0)" ::: "memory");
    }
    if (t < 15) __builtin_amdgcn_s_barrier();
    ta = (ta == 2) ? 0 : ta + 1;
    sa = (sa == 2) ? 0 : sa + 1;
  }

#pragma unroll
  for (int mi = 0; mi < 8; mi++)
#pragma unroll
    for (int ni = 0; ni < 3; ni++) {
      int row0 = bm + wm * 128 + mi * 16 + ih * 4;
      int col = bn + wn * 48 + ni * 16 + il;
      int sec = col >> 10, cc = col & 1023;
      if (sec == 2) {
        int b = row0 >> 11, n = row0 & 2047;
        int bh2 = b * 16 + (cc >> 6), dh = cc & 63;
        union { f16x4 h; uint2 u; } pk;
#pragma unroll
        for (int r = 0; r < 4; r++) pk.h[r] = (_Float16)acc[mi][ni][r];
        *(uint2*)(vt + (size_t)bh2 * 131072 + (size_t)dh * 2048 + n) = pk.u;
      } else {
#pragma unroll
        for (int r = 0; r < 4; r++) {
          int row = row0 + r;
          float v = acc[mi][ni][r];
          if (sec == 0) v *= 0.18033688f;  // fold 0.125*log2(e) into Q
          size_t plane = (size_t)(sec * 32 + (row >> 11) * 16 + (cc >> 6));
          oh[plane * 131072 + (size_t)(row & 2047) * 64 + (cc & 63)] = (_Float16)v;
        }
      }
    }
#undef R15_STAGE_A
#undef R15_STAGE_B
}

// -------------------------- GEMM2: 128x128 1-phase counted (R17 exact) -----
__global__ __launch_bounds__(512) void gemm2p(const _Float16* __restrict__ A,
                                              const _Float16* __restrict__ Bt,
                                              float* __restrict__ of,
                                              const float* __restrict__ bias) {
  __shared__ __align__(16) char smem[81920];
  const int tid = threadIdx.x, wave = tid >> 6, lane = tid & 63;
  const int il = lane & 15, ih = lane >> 4;
  const int rs = lane >> 3, cp = lane & 7;
  const int bm = blockIdx.y * 128, bn = blockIdx.x * 128;
  const int wm = wave >> 2, wn = wave & 3;
  const int srow = wave * 8 + rs;

#define R17_STAGE_A(ABUF, T)                                                  \
  _Pragma("unroll") for (int hh = 0; hh < 2; hh++) {                          \
    int row = hh * 64 + srow;                                                 \
    int c = cp ^ (row & 7);                                                   \
    gload16(A + (size_t)(bm + row) * 1024 + (T) * 64 + c * 8,                 \
            smem + (ABUF) * 16384 + hh * 8192 + wave * 1024);                 \
  }
#define R17_STAGE_B(BBUF, T)                                                  \
  _Pragma("unroll") for (int hh = 0; hh < 2; hh++) {                          \
    int row = hh * 64 + srow;                                                 \
    int c = cp ^ (row & 7);                                                   \
    gload16(Bt + (size_t)(bn + row) * 1024 + (T) * 64 + c * 8,                \
            smem + 49152 + (BBUF) * 16384 + hh * 8192 + wave * 1024);         \
  }

  f32x4 acc[4][2] = {};

  R17_STAGE_A(0, 0);
  R17_STAGE_B(0, 0);
  R17_STAGE_A(1, 1);
  R17_STAGE_B(1, 1);
  asm volatile("s_waitcnt vmcnt(4)" ::: "memory");
  __builtin_amdgcn_s_barrier();

  int ta = 0, sa = 2;
#pragma unroll 1
  for (int t = 0; t < 16; t++) {
    const char* Abuf = (const char*)smem + ta * 16384;
    const char* Bbuf = (const char*)smem + 49152 + (t & 1) * 16384;
    f16x8 af[4][2], bf[2][2];
#pragma unroll
    for (int m = 0; m < 4; m++) {
      int R = wm * 64 + m * 16 + il;
#pragma unroll
      for (int ks = 0; ks < 2; ks++)
        af[m][ks] = *(const f16x8*)(Abuf + R * 128 + (((ks * 4 + ih) ^ (R & 7)) * 16));
    }
#pragma unroll
    for (int n = 0; n < 2; n++) {
      int C = wn * 32 + n * 16 + il;
#pragma unroll
      for (int ks = 0; ks < 2; ks++)
        bf[n][ks] = *(const f16x8*)(Bbuf + C * 128 + (((ks * 4 + ih) ^ (C & 7)) * 16));
    }
    if (t < 14) { R17_STAGE_A(sa, t + 2); }
    asm volatile("s_waitcnt lgkmcnt(0)" ::: "memory");
    __builtin_amdgcn_s_barrier();
    if (t < 14) { R17_STAGE_B(t & 1, t + 2); }
    __builtin_amdgcn_s_setprio(1);
#pragma unroll
    for (int m = 0; m < 4; m++)
#pragma unroll
      for (int n = 0; n < 2; n++)
#pragma unroll
        for (int ks = 0; ks < 2; ks++)
          acc[m][n] = MFMA16(af[m][ks], bf[n][ks], acc[m][n]);
    __builtin_amdgcn_s_setprio(0);
    if (t <= 13) {
      asm volatile("s_waitcnt vmcnt(4)" ::: "memory");
    } else if (t == 14) {
      asm volatile("s_waitcnt vmcnt(0)" ::: "memory");
    }
    if (t < 15) __builtin_amdgcn_s_barrier();
    ta = (ta == 2) ? 0 : ta + 1;
    sa = (sa == 2) ? 0 : sa + 1;
  }

#pragma unroll
  for (int mi = 0; mi < 4; mi++)
#pragma unroll
    for (int ni = 0; ni < 2; ni++) {
      int row0 = bm + wm * 64 + mi * 16 + ih * 4;
      int col = bn + wn * 32 + ni * 16 + il;
#pragma unroll
      for (int r = 0; r < 4; r++)
        of[(size_t)(row0 + r) * 1024 + col] = acc[mi][ni][r] + bias[col];
    }
#undef R17_STAGE_A
#undef R17_STAGE_B
}

// -------------------------- banded flash attention v6 (R18) ----------------
// Compute identical to R11 (in-register P exchange via __shfl_xor).
// Staging: 3 buffers x 16KB at smem {0, 16K, 32K}; Q staged in buf2 and
// consumed into bq registers before the loop (lgkm+barrier certifies all
// waves' reads before L2 overwrites buf2 at iter 0). L(i) lives in
// buf[i%3]; iter i issues L(i+2), computes buf[i%3], then counted
// s_waitcnt vmcnt(2) (steady; 0 in tail) + raw s_barrier — awaited loads
// were issued a full iteration earlier. 48KB LDS -> 3 blocks/CU preserved.
// Ledger (per wave, 2 gloads/tile): steady outstanding at wait = 4
// {L(i+1),L(i+2)} -> vmcnt(2) drains L(i+1), leaves L(i+2) flying.
__global__ __launch_bounds__(512) void attn(const _Float16* __restrict__ QKV,
                                            const _Float16* __restrict__ VT,
                                            _Float16* __restrict__ O2) {
  __shared__ __align__(16) char smem[49152];
  const int tid = threadIdx.x, wave = tid >> 6, lane = tid & 63;
  const int qw = wave >> 1, sh = wave & 1;
  const int cl = lane & 31, hl = lane >> 5;
  const int rs = lane >> 3, cp = lane & 7;
  const int q0 = blockIdx.x * 128, bh = blockIdx.y;
  const _Float16* Qg = QKV + (size_t)bh * 131072;
  const _Float16* Kg = QKV + 4194304 + (size_t)bh * 131072;
  const _Float16* Vg = VT + (size_t)bh * 131072;
  const int t0 = (q0 >= 256) ? q0 - 256 : 0;
  const int t1 = (q0 + 384 <= 2048) ? q0 + 384 : 2048;
  const int niter = (t1 - t0) >> 6;  // >= 6
  const int srow = wave * 8 + rs;
  const int sc = cp ^ (srow & 7);

  // Q -> buf2 (offset 32768)
#pragma unroll
  for (int q = 0; q < 2; q++) {
    int s = 2 * wave + q;
    int row = s * 8 + rs;
    int c = cp ^ (row & 7);
    gload16(Qg + (size_t)(q0 + row) * 64 + c * 8, smem + 32768 + s * 1024);
  }
  // L0 -> buf0, L1 -> buf1 (K at +0, V at +8192 within each buffer)
  gload16(Kg + (size_t)(t0 + srow) * 64 + sc * 8, smem + wave * 1024);
  gload16(Vg + (size_t)srow * 2048 + t0 + sc * 8, smem + 8192 + wave * 1024);
  gload16(Kg + (size_t)(t0 + 64 + srow) * 64 + sc * 8, smem + 16384 + wave * 1024);
  gload16(Vg + (size_t)srow * 2048 + (t0 + 64) + sc * 8, smem + 16384 + 8192 + wave * 1024);
  __syncthreads();  // full drain: Q, L0, L1 resident

  f16x8 bq[4];
  {
    int row = 32 * qw + cl;
#pragma unroll
    for (int ks = 0; ks < 4; ks++)
      bq[ks] = *(const f16x8*)(smem + 32768 + row * 128 + (((ks * 2 + hl) ^ (row & 7)) * 16));
  }
  // certify ALL waves' bq reads complete before buf2 is reused by L2
  asm volatile("s_waitcnt lgkmcnt(0)" ::: "memory");
  __builtin_amdgcn_s_barrier();

  f32x16 oacc[2] = {};
  float l_acc = 0.f;
  const int a0 = q0 + 32 * qw;

  int bc = 0, bs = 2;  // buffer index of L(i) / of L(i+2)
  for (int i = 0; i < niter; i++) {
    const int kt = t0 + i * 64;
    if (i + 2 < niter) {
      char* Bn = smem + bs * 16384;
      gload16(Kg + (size_t)(kt + 128 + srow) * 64 + sc * 8, Bn + wave * 1024);
      gload16(Vg + (size_t)srow * 2048 + (kt + 128) + sc * 8, Bn + 8192 + wave * 1024);
    }
    const int d0 = a0 - (kt + 32 * sh);
    if (d0 < 288 && d0 > -288) {
      char* Ksm = smem + bc * 16384;
      char* Vsm = Ksm + 8192;
      f32x16 st = {};
      {
        const int krow = 32 * sh + cl;
        __builtin_amdgcn_s_setprio(1);
#pragma unroll
        for (int ks = 0; ks < 4; ks++) {
          f16x8 ak = *(const f16x8*)(Ksm + krow * 128 + (((ks * 2 + hl) ^ (krow & 7)) * 16));
          st = MFMA32(ak, bq[ks], st);
        }
        __builtin_amdgcn_s_setprio(0);
      }
      unsigned w0a[4], w1a[4];
#pragma unroll
      for (int g = 0; g < 4; g++) {
        float v[4];
#pragma unroll
        for (int i2 = 0; i2 < 4; i2++) {
          float e = __builtin_amdgcn_exp2f(st[4 * g + i2]);
          int kl = 8 * g + 4 * hl + i2;
          if (d0 == 256) e = (cl <= kl) ? e : 0.f;
          else if (d0 == -256) e = (cl >= kl) ? e : 0.f;
          l_acc += e;
          v[i2] = e;
        }
        w0a[g] = pk2(v[0], v[1]);
        w1a[g] = pk2(v[2], v[3]);
      }
#pragma unroll
      for (int ks2 = 0; ks2 < 2; ks2++) {
        unsigned kA0 = w0a[2 * ks2],     kA1 = w1a[2 * ks2];
        unsigned kB0 = w0a[2 * ks2 + 1], kB1 = w1a[2 * ks2 + 1];
        unsigned keep0 = hl ? kB0 : kA0, keep1 = hl ? kB1 : kA1;
        unsigned send0 = hl ? kA0 : kB0, send1 = hl ? kA1 : kB1;
        unsigned r0 = (unsigned)__shfl_xor((int)send0, 32);
        unsigned r1 = (unsigned)__shfl_xor((int)send1, 32);
        union { unsigned u[4]; f16x8 h; } bp;
        bp.u[0] = hl ? r0 : keep0;
        bp.u[1] = hl ? r1 : keep1;
        bp.u[2] = hl ? keep0 : r0;
        bp.u[3] = hl ? keep1 : r1;
        __builtin_amdgcn_s_setprio(1);
#pragma unroll
        for (int db = 0; db < 2; db++) {
          int vrow = 32 * db + cl;
          f16x8 av = *(const f16x8*)(Vsm + vrow * 128 +
                                     (((4 * sh + 2 * ks2 + hl) ^ (vrow & 7)) * 16));
          oacc[db] = MFMA32(av, bp.h, oacc[db]);
        }
        __builtin_amdgcn_s_setprio(0);
      }
    }
    // counted boundary: L(i+1) must be resident for compute(i+1);
    // keep L(i+2) (2 loads) in flight when it exists.
    if (i + 2 < niter) {
      asm volatile("s_waitcnt vmcnt(2)" ::: "memory");
    } else {
      asm volatile("s_waitcnt vmcnt(0)" ::: "memory");
    }
    __builtin_amdgcn_s_barrier();
    bc = (bc == 2) ? 0 : bc + 1;
    bs = (bs == 2) ? 0 : bs + 1;
  }
  __syncthreads();  // all compute + DMA done before Mq/lp overlay buffers

  const float lp = l_acc + __shfl_xor(l_acc, 32);
  char* Mq = smem + qw * 8448;
  if (sh == 1) {
#pragma unroll
    for (int db = 0; db < 2; db++)
#pragma unroll
      for (int g = 0; g < 4; g++) {
        int dh0 = 32 * db + 8 * g + 4 * hl;
        f32x2 a = {oacc[db][4 * g + 0], oacc[db][4 * g + 1]};
        f32x2 b = {oacc[db][4 * g + 2], oacc[db][4 * g + 3]};
        *(f32x2*)(Mq + cl * 264 + dh0 * 4) = a;
        *(f32x2*)(Mq + cl * 264 + dh0 * 4 + 8) = b;
      }
    if (hl == 0) *(float*)(smem + 34816 + (qw * 32 + cl) * 4) = lp;
  }
  __syncthreads();
  if (sh == 0) {
    float lo = *(const float*)(smem + 34816 + (qw * 32 + cl) * 4);
    float inv = 1.0f / (lp + lo);
    const int b = bh >> 4, h = bh & 15;
    _Float16* dst = O2 + (size_t)(b * 2048 + a0 + cl) * 1024 + h * 64;
#pragma unroll
    for (int db = 0; db < 2; db++)
#pragma unroll
      for (int g = 0; g < 4; g++) {
        int dh0 = 32 * db + 8 * g + 4 * hl;
        f32x2 a = *(const f32x2*)(Mq + cl * 264 + dh0 * 4);
        f32x2 b2 = *(const f32x2*)(Mq + cl * 264 + dh0 * 4 + 8);
        uint2 pkd = {pk2((oacc[db][4 * g + 0] + a[0]) * inv,
                         (oacc[db][4 * g + 1] + a[1]) * inv),
                     pk2((oacc[db][4 * g + 2] + b2[0]) * inv,
                         (oacc[db][4 * g + 3] + b2[1]) * inv)};
        *(uint2*)(dst + dh0) = pkd;
      }
  }
}

// -------------------------- host launch ------------------------------------

extern "C" void kernel_launch(void* const* d_in, const int* in_sizes, int n_in,
                              void* d_out, int out_size, void* d_ws, size_t ws_size,
                              hipStream_t stream) {
  const float* x = (const float*)d_in[0];
  const float* wqkv = (const float*)d_in[1];
  const float* wproj = (const float*)d_in[2];
  const float* bproj = (const float*)d_in[3];
  float* out = (float*)d_out;
  char* ws = (char*)d_ws;

  _Float16* Xb  = (_Float16*)(ws);                       // 8 MB [4096][1024]
  _Float16* Wqt = (_Float16*)(ws + (size_t)(8  << 20));  // 6 MB [3072][1024]
  _Float16* Wpt = (_Float16*)(ws + (size_t)(14 << 20));  // 2 MB [1024][1024]
  _Float16* QKV = (_Float16*)(ws + (size_t)(16 << 20));  // 16 MB Q,K planes
  _Float16* Vt  = (_Float16*)(ws + (size_t)(40 << 20));  // 8 MB [32][64][2048]
  _Float16* O2  = (_Float16*)(ws);                       // aliases Xb

  prep<<<5120, 256, 0, stream>>>(x, wqkv, wproj, Xb, Wqt, Wpt);
  gemm8p<<<dim3(16, 16), 512, 0, stream>>>(Xb, Wqt, QKV, Vt);
  attn<<<dim3(16, 32), 512, 0, stream>>>(QKV, Vt, O2);
  gemm2p<<<dim3(8, 32), 512, 0, stream>>>(O2, Wpt, out, bproj);
}